// Round 1
// baseline (637.132 us; speedup 1.0000x reference)
//
#include <hip/hip_runtime.h>
#include <hip/hip_bf16.h>

#define CH 384
#define HH 56
#define WW 56
#define HW (HH*WW)

// Scale-folded effective weights (u in {-1,0,1} times scalar scale -> exact fp32).
__device__ float g_wdw_eff[CH * 9];        // [o][tap]
__device__ float g_wpwT_eff[CH * CH];      // transposed: [ci][co]

__global__ __launch_bounds__(1024) void prep_kernel(const float* __restrict__ wdw,
                                                    const float* __restrict__ wpw) {
    const int tid = threadIdx.x;

    // ---- depthwise per-channel quant (independent; threads 0..383) ----
    if (tid < CH) {
        const float* w = wdw + tid * 9;
        float asum = 0.f;
        #pragma unroll
        for (int t = 0; t < 9; ++t) asum += fabsf(w[t]);
        const float m   = asum / 9.0f;
        const float mx  = fmaxf(m, 1e-5f);
        const float sc  = 1.0f / mx;
        #pragma unroll
        for (int t = 0; t < 9; ++t) {
            float u = rintf(w[t] * sc);           // jnp.round == RNE
            u = fminf(1.f, fmaxf(-1.f, u));
            g_wdw_eff[tid * 9 + t] = u * mx;      // exact product
        }
    }

    // ---- pointwise global mean|w| in fp64 (deterministic tree) ----
    double s = 0.0;
    for (int i = tid; i < CH * CH; i += 1024) s += (double)fabsf(wpw[i]);
    #pragma unroll
    for (int off = 32; off > 0; off >>= 1) s += __shfl_down(s, off, 64);

    __shared__ double sred[16];
    if ((tid & 63) == 0) sred[tid >> 6] = s;
    __syncthreads();

    __shared__ float s_scale, s_mx;
    if (tid == 0) {
        double tot = 0.0;
        #pragma unroll
        for (int i = 0; i < 16; ++i) tot += sred[i];
        const float mean = (float)(tot / (double)(CH * CH));
        const float mx   = fmaxf(mean, 1e-5f);
        s_mx = mx;
        s_scale = 1.0f / mx;
    }
    __syncthreads();

    const float scale = s_scale, mx = s_mx;
    for (int i = tid; i < CH * CH; i += 1024) {
        float u = rintf(wpw[i] * scale);
        u = fminf(1.f, fmaxf(-1.f, u));
        const int co = i / CH, ci = i % CH;
        g_wpwT_eff[ci * CH + co] = u * mx;        // exact product, transposed
    }
}

// One block per (n, h). Phase 1: depthwise -> y row in LDS (bf16, 43 KB -> 3 blocks/CU).
// Phase 2: pointwise, 4co x 7w register micro-tiles, 3 tiles/thread.
__global__ __launch_bounds__(256) void fused_kernel(const float* __restrict__ x,
                                                    float* __restrict__ out) {
    __shared__ __hip_bfloat16 ylds[CH][WW];   // 384*56*2 = 43008 B

    const int blk = blockIdx.x;
    const int n = blk / HH, h = blk % HH;
    const float* xn = x + (size_t)n * CH * HW;

    // ---- phase 1: depthwise conv for this row, all 384 channels ----
    for (int unit = threadIdx.x; unit < CH * 8; unit += 256) {
        const int ci = unit >> 3;
        const int w0 = (unit & 7) * 7;
        const float* xp = xn + (size_t)ci * HW;
        const float* wd = g_wdw_eff + ci * 9;
        float acc[7] = {0.f, 0.f, 0.f, 0.f, 0.f, 0.f, 0.f};
        #pragma unroll
        for (int dy = -1; dy <= 1; ++dy) {
            const int hh = h + dy;
            if (hh < 0 || hh >= HH) continue;       // zero padding (rows)
            const float* row = xp + hh * WW;
            float xv[9];
            #pragma unroll
            for (int t = 0; t < 9; ++t) {
                const int c = w0 - 1 + t;
                xv[t] = (c >= 0 && c < WW) ? row[c] : 0.0f;  // zero padding (cols)
            }
            #pragma unroll
            for (int dx = 0; dx < 3; ++dx) {
                const float wv = wd[(dy + 1) * 3 + dx];
                #pragma unroll
                for (int j = 0; j < 7; ++j) acc[j] += xv[j + dx] * wv;
            }
        }
        #pragma unroll
        for (int j = 0; j < 7; ++j) ylds[ci][w0 + j] = __float2bfloat16(acc[j]);
    }
    __syncthreads();

    // ---- phase 2: pointwise (K=384 dot per output) ----
    float* obase = out + (size_t)n * CH * HW + h * WW;
    for (int tile = threadIdx.x; tile < 768; tile += 256) {
        const int co0 = (tile % 96) * 4;
        const int w0  = (tile / 96) * 7;
        float acc[4][7];
        #pragma unroll
        for (int i = 0; i < 4; ++i)
            #pragma unroll
            for (int j = 0; j < 7; ++j) acc[i][j] = 0.f;

        const float* wp = g_wpwT_eff + co0;       // [ci][co], coalesced float4
        for (int k = 0; k < CH; ++k) {
            float yv[7];
            #pragma unroll
            for (int j = 0; j < 7; ++j) yv[j] = __bfloat162float(ylds[k][w0 + j]);
            const float4 wv = *reinterpret_cast<const float4*>(wp + (size_t)k * CH);
            const float wf[4] = {wv.x, wv.y, wv.z, wv.w};
            #pragma unroll
            for (int i = 0; i < 4; ++i)
                #pragma unroll
                for (int j = 0; j < 7; ++j) acc[i][j] += wf[i] * yv[j];
        }
        #pragma unroll
        for (int i = 0; i < 4; ++i)
            #pragma unroll
            for (int j = 0; j < 7; ++j)
                obase[(size_t)(co0 + i) * HW + (w0 + j)] = acc[i][j];
    }
}

extern "C" void kernel_launch(void* const* d_in, const int* in_sizes, int n_in,
                              void* d_out, int out_size, void* d_ws, size_t ws_size,
                              hipStream_t stream) {
    const float* x    = (const float*)d_in[0];   // (16,384,56,56)
    const float* w_dw = (const float*)d_in[1];   // (384,1,3,3)
    const float* w_pw = (const float*)d_in[2];   // (384,384,1,1)
    float* out = (float*)d_out;

    prep_kernel<<<1, 1024, 0, stream>>>(w_dw, w_pw);
    fused_kernel<<<16 * HH, 256, 0, stream>>>(x, out);
}

// Round 2
// 141.466 us; speedup vs baseline: 4.5038x; 4.5038x over previous
//
#include <hip/hip_runtime.h>
#include <hip/hip_bf16.h>

#define CH 384
#define HH 56
#define WW 56
#define HW (HH*WW)
#define YPITCH 392          // ci stride in LDS: 384 + 8 pad (breaks bank alias)
#define PIXPAD 64           // 56 pixels padded to 4 tiles of 16

typedef __attribute__((ext_vector_type(4))) float f32x4;
typedef __attribute__((ext_vector_type(8))) short bf16x8;

// Prepared weights
__device__ float          g_wdw_eff[CH * 9];   // depthwise: u*mx exact in fp32, [o][tap]
__device__ __hip_bfloat16 g_wpw_u[CH * CH];    // pointwise: ternary u exact in bf16, [co][ci]
__device__ float          g_mx_pw;             // pointwise scale (multiply epilogue)

__global__ __launch_bounds__(1024) void prep_kernel(const float* __restrict__ wdw,
                                                    const float* __restrict__ wpw) {
    const int tid = threadIdx.x;

    // ---- depthwise per-channel quant (threads 0..383) ----
    if (tid < CH) {
        const float* w = wdw + tid * 9;
        float asum = 0.f;
        #pragma unroll
        for (int t = 0; t < 9; ++t) asum += fabsf(w[t]);
        const float m  = asum / 9.0f;
        const float mx = fmaxf(m, 1e-5f);
        const float sc = 1.0f / mx;
        #pragma unroll
        for (int t = 0; t < 9; ++t) {
            float u = rintf(w[t] * sc);          // jnp.round == RNE
            u = fminf(1.f, fmaxf(-1.f, u));
            g_wdw_eff[tid * 9 + t] = u * mx;     // exact product in fp32
        }
    }

    // ---- pointwise global mean|w| in fp64 (deterministic) ----
    double s = 0.0;
    for (int i = tid; i < CH * CH; i += 1024) s += (double)fabsf(wpw[i]);
    #pragma unroll
    for (int off = 32; off > 0; off >>= 1) s += __shfl_down(s, off, 64);

    __shared__ double sred[16];
    if ((tid & 63) == 0) sred[tid >> 6] = s;
    __syncthreads();

    __shared__ float s_scale;
    if (tid == 0) {
        double tot = 0.0;
        #pragma unroll
        for (int i = 0; i < 16; ++i) tot += sred[i];
        const float mean = (float)(tot / (double)(CH * CH));
        const float mx   = fmaxf(mean, 1e-5f);
        g_mx_pw = mx;
        s_scale = 1.0f / mx;
    }
    __syncthreads();

    const float scale = s_scale;
    for (int i = tid; i < CH * CH; i += 1024) {
        float u = rintf(wpw[i] * scale);
        u = fminf(1.f, fmaxf(-1.f, u));
        g_wpw_u[i] = __float2bfloat16(u);        // {-1,0,1} exact in bf16
    }
}

// One block per (n, h): depthwise -> y[pix][ci] bf16 LDS -> MFMA pointwise.
__global__ __launch_bounds__(512, 4) void fused_kernel(const float* __restrict__ x,
                                                       float* __restrict__ out) {
    __shared__ __attribute__((aligned(16))) __hip_bfloat16 ylds[PIXPAD * YPITCH]; // 50176 B

    const int blk = blockIdx.x;
    const int n = blk / HH, h = blk % HH;
    const float* xn = x + (size_t)n * CH * HW;

    // ---- phase 1: depthwise conv for this row, all 384 channels ----
    for (int unit = threadIdx.x; unit < CH * 8; unit += 512) {
        const int ci = unit >> 3;
        const int w0 = (unit & 7) * 7;
        const float* xp = xn + (size_t)ci * HW;
        const float* wd = g_wdw_eff + ci * 9;
        float acc[7] = {0.f, 0.f, 0.f, 0.f, 0.f, 0.f, 0.f};
        #pragma unroll
        for (int dy = -1; dy <= 1; ++dy) {
            const int hh = h + dy;
            if (hh < 0 || hh >= HH) continue;            // zero pad rows
            const float* row = xp + hh * WW;
            float xv[9];
            #pragma unroll
            for (int t = 0; t < 9; ++t) {
                const int c = w0 - 1 + t;
                xv[t] = (c >= 0 && c < WW) ? row[c] : 0.0f;  // zero pad cols
            }
            #pragma unroll
            for (int dx = 0; dx < 3; ++dx) {
                const float wv = wd[(dy + 1) * 3 + dx];
                #pragma unroll
                for (int j = 0; j < 7; ++j) acc[j] += xv[j + dx] * wv;
            }
        }
        #pragma unroll
        for (int j = 0; j < 7; ++j)
            ylds[(w0 + j) * YPITCH + ci] = __float2bfloat16(acc[j]);  // transposed store
    }
    __syncthreads();

    // ---- phase 2: pointwise GEMM via MFMA ----
    // out[co][pix] = sum_ci U[co][ci] * y[ci][pix], then * mx_pw
    const int wv   = threadIdx.x >> 6;     // wave 0..7
    const int lane = threadIdx.x & 63;
    const int lr   = lane & 15;            // row (A) / col (B,D)
    const int lk   = lane >> 4;            // k-group

    f32x4 acc[3][4];
    #pragma unroll
    for (int i = 0; i < 3; ++i)
        #pragma unroll
        for (int j = 0; j < 4; ++j) acc[i][j] = (f32x4){0.f, 0.f, 0.f, 0.f};

    for (int k0 = 0; k0 < CH; k0 += 32) {
        bf16x8 bfr[4];
        #pragma unroll
        for (int j = 0; j < 4; ++j)
            bfr[j] = *reinterpret_cast<const bf16x8*>(
                &ylds[(16 * j + lr) * YPITCH + k0 + 8 * lk]);
        #pragma unroll
        for (int i = 0; i < 3; ++i) {
            const int co = (wv + 8 * i) * 16 + lr;      // waves interleaved over co
            bf16x8 afr = *reinterpret_cast<const bf16x8*>(
                &g_wpw_u[(size_t)co * CH + k0 + 8 * lk]);
            #pragma unroll
            for (int j = 0; j < 4; ++j)
                acc[i][j] = __builtin_amdgcn_mfma_f32_16x16x32_bf16(afr, bfr[j], acc[i][j], 0, 0, 0);
        }
    }

    // ---- epilogue: D layout col=lane&15 (pix), row=(lane>>4)*4+reg (co) ----
    const float s = g_mx_pw;
    float* obase = out + (size_t)n * CH * HW + (size_t)h * WW;
    #pragma unroll
    for (int j = 0; j < 4; ++j) {
        const int pix = 16 * j + lr;
        if (pix >= WW) continue;
        #pragma unroll
        for (int i = 0; i < 3; ++i) {
            const int co0 = (wv + 8 * i) * 16 + lk * 4;
            #pragma unroll
            for (int r = 0; r < 4; ++r)
                obase[(size_t)(co0 + r) * HW + pix] = acc[i][j][r] * s;
        }
    }
}

extern "C" void kernel_launch(void* const* d_in, const int* in_sizes, int n_in,
                              void* d_out, int out_size, void* d_ws, size_t ws_size,
                              hipStream_t stream) {
    const float* x    = (const float*)d_in[0];   // (16,384,56,56)
    const float* w_dw = (const float*)d_in[1];   // (384,1,3,3)
    const float* w_pw = (const float*)d_in[2];   // (384,384,1,1)
    float* out = (float*)d_out;

    prep_kernel<<<1, 1024, 0, stream>>>(w_dw, w_pw);
    fused_kernel<<<16 * HH, 512, 0, stream>>>(x, out);
}